// Round 1
// baseline (5998.100 us; speedup 1.0000x reference)
//
#include <hip/hip_runtime.h>
#include <cstdint>

#define B_   128
#define T_   30
#define F_   2048
#define E_   512
#define H_   512
#define A_   512
#define CD_  128
#define CV_  64
#define V_   10000
#define NN_  49
#define G4_  2048   // 4*H
#define LCAP_ 31

// ---------------- generic fp32 GEMM: C = act(A(M,K) @ Bt(N,K)^T + bias) ----------------
// 64x64 tile, BK=16, 256 threads, 4x4 micro-tile. lda/ldb/ldc arbitrary (mult of 4).
template<int ACT>  // 0 = none, 1 = tanh
__global__ __launch_bounds__(256)
void gemm_nt(const float* __restrict__ A, int lda,
             const float* __restrict__ Bt, int ldb,
             const float* __restrict__ bias,
             float* __restrict__ C, int ldc,
             int M, int N, int K) {
  __shared__ float As[16][64];
  __shared__ float Bs[16][64];
  const int tid = threadIdx.x;
  const int tx = tid & 15, ty = tid >> 4;
  const int n0 = blockIdx.x * 64, m0 = blockIdx.y * 64;
  const int lrow = tid >> 2, lkq = (tid & 3) << 2;
  const bool aval = (m0 + lrow) < M;
  const bool bval = (n0 + lrow) < N;
  const float* Ap = A  + (size_t)(m0 + lrow) * lda + lkq;
  const float* Bp = Bt + (size_t)(n0 + lrow) * ldb + lkq;
  float acc[4][4] = {};
  for (int k0 = 0; k0 < K; k0 += 16) {
    float4 av = make_float4(0.f, 0.f, 0.f, 0.f);
    float4 bv = make_float4(0.f, 0.f, 0.f, 0.f);
    if (aval) av = *(const float4*)(Ap + k0);
    if (bval) bv = *(const float4*)(Bp + k0);
    __syncthreads();
    As[lkq+0][lrow] = av.x; As[lkq+1][lrow] = av.y;
    As[lkq+2][lrow] = av.z; As[lkq+3][lrow] = av.w;
    Bs[lkq+0][lrow] = bv.x; Bs[lkq+1][lrow] = bv.y;
    Bs[lkq+2][lrow] = bv.z; Bs[lkq+3][lrow] = bv.w;
    __syncthreads();
#pragma unroll
    for (int k = 0; k < 16; ++k) {
      float a4[4], b4[4];
#pragma unroll
      for (int i = 0; i < 4; ++i) a4[i] = As[k][ty*4 + i];
#pragma unroll
      for (int j = 0; j < 4; ++j) b4[j] = Bs[k][tx*4 + j];
#pragma unroll
      for (int i = 0; i < 4; ++i)
#pragma unroll
        for (int j = 0; j < 4; ++j)
          acc[i][j] += a4[i] * b4[j];
    }
  }
#pragma unroll
  for (int i = 0; i < 4; ++i) {
    int m = m0 + ty*4 + i;
    if (m >= M) continue;
#pragma unroll
    for (int j = 0; j < 4; ++j) {
      int n = n0 + tx*4 + j;
      if (n >= N) continue;
      float v = acc[i][j];
      if (bias) v += bias[n];
      if (ACT == 1) v = tanhf(v);
      C[(size_t)m * ldc + n] = v;
    }
  }
}

// ---------------- att_feats (B,F,49) -> att_t (B,49,F) ----------------
__global__ __launch_bounds__(256)
void transpose_att(const float* __restrict__ af, float* __restrict__ att_t) {
  __shared__ float s[64 * NN_];
  const int b = blockIdx.y, f0 = blockIdx.x * 64;
  const float* src = af + (size_t)b * F_ * NN_ + (size_t)f0 * NN_;
  for (int i = threadIdx.x; i < 64 * NN_; i += 256) s[i] = src[i];
  __syncthreads();
  float* dst = att_t + (size_t)b * NN_ * F_ + f0;
  for (int i = threadIdx.x; i < NN_ * 64; i += 256) {
    int n = i >> 6, j = i & 63;
    dst[(size_t)n * F_ + j] = s[j * NN_ + n];
  }
}

// ---------------- count-embed 2-layer MLP ----------------
__global__ __launch_bounds__(128)
void count_embed_k(const float* __restrict__ cv, const float* __restrict__ w1,
                   const float* __restrict__ b1, const float* __restrict__ w2,
                   const float* __restrict__ b2, float* __restrict__ ce) {
  const int b = blockIdx.x, tid = threadIdx.x;  // 128 threads
  __shared__ float s_cv[CV_], s_h[CD_];
  if (tid < CV_) s_cv[tid] = cv[b * CV_ + tid];
  __syncthreads();
  float acc = b1[tid];
  for (int k = 0; k < CV_; ++k) acc += s_cv[k] * w1[tid * CV_ + k];
  s_h[tid] = fmaxf(acc, 0.f);
  __syncthreads();
  float acc2 = b2[tid];
  for (int k = 0; k < CD_; ++k) acc2 += s_h[k] * w2[tid * CD_ + k];
  ce[b * CD_ + tid] = acc2;
}

// ---------------- gather word embeddings: we[(b*T+t)] = embed_w[captions[b][t]] ----------------
__global__ __launch_bounds__(128)
void gather_we(const int* __restrict__ captions, const float* __restrict__ embed_w,
               float* __restrict__ we) {
  const int r = blockIdx.x;           // b*T + t
  const int b = r / T_, t = r - b * T_;
  const int idx = captions[b * LCAP_ + t];
  const float4* src = (const float4*)(embed_w + (size_t)idx * E_);
  float4* dst = (float4*)(we + (size_t)r * E_);
  dst[threadIdx.x] = src[threadIdx.x];
}

__global__ void addvec_k(const float* __restrict__ a, const float* __restrict__ b,
                         float* __restrict__ o, int n) {
  int i = blockIdx.x * 256 + threadIdx.x;
  if (i < n) o[i] = a[i] + b[i];
}

__global__ void zero_k(float* __restrict__ p, int n) {
  int i = blockIdx.x * 256 + threadIdx.x;
  if (i < n) p[i] = 0.f;
}

// ---------------- per-step attention scores + softmax ----------------
__global__ __launch_bounds__(256)
void attn_step(const float* __restrict__ att_proj, const float* __restrict__ hp,
               const float* __restrict__ alpha_w, const float* __restrict__ alpha_b,
               float* __restrict__ alpha, float* __restrict__ out_alpha, int t) {
  const int b = blockIdx.x;
  const int tid = threadIdx.x;
  const int wv = tid >> 6, lane = tid & 63;
  __shared__ float s_hp[A_], s_aw[A_], s_sc[NN_];
  for (int a = tid; a < A_; a += 256) { s_hp[a] = hp[b * A_ + a]; s_aw[a] = alpha_w[a]; }
  __syncthreads();
  const float ab = alpha_b[0];
  for (int n = wv; n < NN_; n += 4) {
    const float* ap = att_proj + ((size_t)b * NN_ + n) * A_;
    float s = 0.f;
    for (int a = lane; a < A_; a += 64)
      s += tanhf(ap[a] + s_hp[a]) * s_aw[a];
#pragma unroll
    for (int off = 32; off > 0; off >>= 1) s += __shfl_down(s, off);
    if (lane == 0) s_sc[n] = s + ab;
  }
  __syncthreads();
  if (wv == 0) {
    float v = (lane < NN_) ? s_sc[lane] : -3.0e38f;
    float m = v;
#pragma unroll
    for (int off = 32; off > 0; off >>= 1) m = fmaxf(m, __shfl_xor(m, off));
    float e = (lane < NN_) ? __expf(v - m) : 0.f;
    float ssum = e;
#pragma unroll
    for (int off = 32; off > 0; off >>= 1) ssum += __shfl_xor(ssum, off);
    float a = e / ssum;
    if (lane < NN_) {
      alpha[b * NN_ + lane] = a;
      out_alpha[((size_t)b * T_ + t) * NN_ + lane] = a;
    }
  }
}

// ---------------- per-step gates: h@w_hh^T + alpha@attW + base + we_proj[t] ----------------
__global__ __launch_bounds__(256)
void gates_step(const float* __restrict__ h_cur, const float* __restrict__ w_hh,
                const float* __restrict__ alpha, const float* __restrict__ attW,
                const float* __restrict__ we_proj, const float* __restrict__ base,
                float* __restrict__ gates, int t) {
  __shared__ float As[16][64];
  __shared__ float Bs[16][64];
  __shared__ float s_alpha[64][NN_];
  const int tid = threadIdx.x;
  const int tx = tid & 15, ty = tid >> 4;
  const int g0 = blockIdx.x * 64, b0 = blockIdx.y * 64;
  const int lrow = tid >> 2, lkq = (tid & 3) << 2;
  float acc[4][4] = {};
  const float* Ap = h_cur + (size_t)(b0 + lrow) * H_ + lkq;
  const float* Bp = w_hh  + (size_t)(g0 + lrow) * H_ + lkq;
  for (int k0 = 0; k0 < H_; k0 += 16) {
    float4 av = *(const float4*)(Ap + k0);
    float4 bv = *(const float4*)(Bp + k0);
    __syncthreads();
    As[lkq+0][lrow] = av.x; As[lkq+1][lrow] = av.y;
    As[lkq+2][lrow] = av.z; As[lkq+3][lrow] = av.w;
    Bs[lkq+0][lrow] = bv.x; Bs[lkq+1][lrow] = bv.y;
    Bs[lkq+2][lrow] = bv.z; Bs[lkq+3][lrow] = bv.w;
    __syncthreads();
#pragma unroll
    for (int k = 0; k < 16; ++k) {
      float a4[4], b4[4];
#pragma unroll
      for (int i = 0; i < 4; ++i) a4[i] = As[k][ty*4 + i];
#pragma unroll
      for (int j = 0; j < 4; ++j) b4[j] = Bs[k][tx*4 + j];
#pragma unroll
      for (int i = 0; i < 4; ++i)
#pragma unroll
        for (int j = 0; j < 4; ++j)
          acc[i][j] += a4[i] * b4[j];
    }
  }
  __syncthreads();
  for (int i = tid; i < 64 * NN_; i += 256) {
    int bb = i / NN_, nn = i - bb * NN_;
    s_alpha[bb][nn] = alpha[(b0 + bb) * NN_ + nn];
  }
  __syncthreads();
  for (int n = 0; n < NN_; ++n) {
#pragma unroll
    for (int i = 0; i < 4; ++i) {
      const int bb = ty*4 + i;
      const float a = s_alpha[bb][n];
      const float4 w = *(const float4*)(attW + (((size_t)(b0 + bb) * NN_ + n) << 11) + g0 + tx*4);
      acc[i][0] += a * w.x; acc[i][1] += a * w.y;
      acc[i][2] += a * w.z; acc[i][3] += a * w.w;
    }
  }
#pragma unroll
  for (int i = 0; i < 4; ++i) {
    const int b = b0 + ty*4 + i;
#pragma unroll
    for (int j = 0; j < 4; ++j) {
      const int g = g0 + tx*4 + j;
      gates[(size_t)b * G4_ + g] = acc[i][j] + base[(size_t)b * G4_ + g]
                                 + we_proj[((size_t)b * T_ + t) * G4_ + g];
    }
  }
}

// ---------------- LSTM cell elementwise ----------------
__global__ __launch_bounds__(256)
void lstm_cell(const float* __restrict__ gates, float* __restrict__ h_cur,
               float* __restrict__ c_cur, float* __restrict__ H_all, int t) {
  const int i = blockIdx.x * 256 + threadIdx.x;   // < B_*H_
  const int b = i >> 9, j = i & 511;
  const float* gr = gates + (size_t)b * G4_;
  const float gi = gr[j], gf = gr[H_ + j], gg = gr[2*H_ + j], go = gr[3*H_ + j];
  const float si = 1.f / (1.f + __expf(-gi));
  const float sf = 1.f / (1.f + __expf(-gf));
  const float so = 1.f / (1.f + __expf(-go));
  const float c  = c_cur[i];
  const float cn = sf * c + si * tanhf(gg);
  const float hn = so * tanhf(cn);
  c_cur[i] = cn;
  h_cur[i] = hn;
  H_all[((size_t)b * T_ + t) * H_ + j] = hn;
}

extern "C" void kernel_launch(void* const* d_in, const int* in_sizes, int n_in,
                              void* d_out, int out_size, void* d_ws, size_t ws_size,
                              hipStream_t stream) {
  const float* att_feats  = (const float*)d_in[0];
  const float* fc_feats   = (const float*)d_in[1];
  const int*   captions   = (const int*)  d_in[2];
  const float* count_vecs = (const float*)d_in[3];
  const float* embed_w    = (const float*)d_in[4];
  const float* cm_w1      = (const float*)d_in[5];
  const float* cm_b1      = (const float*)d_in[6];
  const float* cm_w2      = (const float*)d_in[7];
  const float* cm_b2      = (const float*)d_in[8];
  const float* att_hw     = (const float*)d_in[9];
  const float* att_hb     = (const float*)d_in[10];
  const float* att_fw     = (const float*)d_in[11];
  const float* att_fb     = (const float*)d_in[12];
  const float* alpha_w    = (const float*)d_in[13];
  const float* alpha_b    = (const float*)d_in[14];
  const float* fcproj_w   = (const float*)d_in[15];
  const float* fcproj_b   = (const float*)d_in[16];
  const float* w_ih       = (const float*)d_in[17];
  const float* b_ih       = (const float*)d_in[18];
  const float* w_hh       = (const float*)d_in[19];
  const float* b_hh       = (const float*)d_in[20];
  const float* fc_w       = (const float*)d_in[21];
  const float* fc_b       = (const float*)d_in[22];
  float* out = (float*)d_out;
  float* ws  = (float*)d_ws;

  // workspace layout (floats)
  size_t off = 0;
  auto nxt = [&](size_t n) { float* p = ws + off; off += (n + 255) & ~(size_t)255; return p; };
  float* att_t    = nxt((size_t)B_ * NN_ * F_);   // 12,845,056
  float* attW     = nxt((size_t)B_ * NN_ * G4_);  // 12,845,056
  float* att_proj = nxt((size_t)B_ * NN_ * A_);   //  3,211,264
  float* we       = nxt((size_t)B_ * T_ * E_);    //  1,966,080
  float* we_proj  = nxt((size_t)B_ * T_ * G4_);   //  7,864,320
  float* H_all    = nxt((size_t)B_ * T_ * H_);    //  1,966,080
  float* ce       = nxt((size_t)B_ * CD_);
  float* base     = nxt((size_t)B_ * G4_);
  float* bsum     = nxt((size_t)G4_);
  float* h_cur    = nxt((size_t)B_ * H_);
  float* c_cur    = nxt((size_t)B_ * H_);
  float* hp       = nxt((size_t)B_ * A_);
  float* alpha    = nxt((size_t)B_ * NN_);
  float* gates    = nxt((size_t)B_ * G4_);
  if (off * sizeof(float) > ws_size) return;  // ws too small: fail loudly (output stays zero)

  const size_t ALPHA_OFF = (size_t)B_ * T_ * V_;  // 38,400,000

  // ---- parallel precompute ----
  transpose_att<<<dim3(F_/64, B_), 256, 0, stream>>>(att_feats, att_t);
  count_embed_k<<<B_, 128, 0, stream>>>(count_vecs, cm_w1, cm_b1, cm_w2, cm_b2, ce);
  addvec_k<<<(G4_ + 255)/256, 256, 0, stream>>>(b_ih, b_hh, bsum, G4_);
  gather_we<<<B_ * T_, 128, 0, stream>>>(captions, embed_w, we);
  zero_k<<<(B_*H_ + 255)/256, 256, 0, stream>>>(c_cur, B_*H_);
  // h0 = tanh(fc_feats @ fcproj_w^T + b)
  gemm_nt<1><<<dim3(H_/64, B_/64), 256, 0, stream>>>(fc_feats, F_, fcproj_w, F_, fcproj_b,
                                                     h_cur, H_, B_, H_, F_);
  // att_proj = att_t @ att_fw^T + att_fb   (6272 x 512, K=2048)
  gemm_nt<0><<<dim3(A_/64, (B_*NN_)/64), 256, 0, stream>>>(att_t, F_, att_fw, F_, att_fb,
                                                           att_proj, A_, B_*NN_, A_, F_);
  // attW = att_t @ w_ih[:, E:E+F]^T        (6272 x 2048, K=2048)
  gemm_nt<0><<<dim3(G4_/64, (B_*NN_)/64), 256, 0, stream>>>(att_t, F_, w_ih + E_, E_ + F_ + CD_,
                                                            nullptr, attW, G4_, B_*NN_, G4_, F_);
  // we_proj = we @ w_ih[:, 0:E]^T          (3840 x 2048, K=512)
  gemm_nt<0><<<dim3(G4_/64, (B_*T_)/64), 256, 0, stream>>>(we, E_, w_ih, E_ + F_ + CD_,
                                                           nullptr, we_proj, G4_, B_*T_, G4_, E_);
  // base = ce @ w_ih[:, E+F:]^T + (b_ih + b_hh)   (128 x 2048, K=128)
  gemm_nt<0><<<dim3(G4_/64, B_/64), 256, 0, stream>>>(ce, CD_, w_ih + E_ + F_, E_ + F_ + CD_,
                                                      bsum, base, G4_, B_, G4_, CD_);

  // ---- sequential scan ----
  for (int t = 0; t < T_; ++t) {
    // hp = h @ att_hw^T + att_hb
    gemm_nt<0><<<dim3(A_/64, B_/64), 256, 0, stream>>>(h_cur, H_, att_hw, H_, att_hb,
                                                       hp, A_, B_, A_, H_);
    attn_step<<<B_, 256, 0, stream>>>(att_proj, hp, alpha_w, alpha_b, alpha,
                                      out + ALPHA_OFF, t);
    gates_step<<<dim3(G4_/64, B_/64), 256, 0, stream>>>(h_cur, w_hh, alpha, attW,
                                                        we_proj, base, gates, t);
    lstm_cell<<<(B_*H_)/256, 256, 0, stream>>>(gates, h_cur, c_cur, H_all, t);
  }

  // ---- logits = H_all @ fc_w^T + fc_b  -> out (B,T,V) rows are (b*T+t) contiguous ----
  gemm_nt<0><<<dim3((V_ + 63)/64, (B_*T_)/64), 256, 0, stream>>>(H_all, H_, fc_w, H_, fc_b,
                                                                 out, V_, B_*T_, V_, H_);
}

// Round 2
// 4178.542 us; speedup vs baseline: 1.4355x; 1.4355x over previous
//
#include <hip/hip_runtime.h>
#include <cstdint>

#define B_   128
#define T_   30
#define F_   2048
#define E_   512
#define H_   512
#define A_   512
#define CD_  128
#define CV_  64
#define V_   10000
#define VP_  10112   // V padded to multiple of 128
#define NN_  49
#define G4_  2048   // 4*H
#define LCAP_ 31

typedef __attribute__((ext_vector_type(4))) float f32x4;
typedef __attribute__((ext_vector_type(8))) short s16x8;

__device__ __forceinline__ unsigned short f2bf(float f) {
  unsigned u = __float_as_uint(f);
  unsigned r = (u + 0x7FFFu + ((u >> 16) & 1u)) >> 16;
  return (unsigned short)r;
}
__device__ __forceinline__ float bf2f(unsigned short u) {
  return __uint_as_float(((unsigned)u) << 16);
}

// ================= bf16 MFMA GEMM: C = A(M,K) @ B(N,K)^T (+bias) =================
// 128x128 tile, BK=32, 256 threads (4 waves 2x2), m97-style global_load_lds staging.
// M, N multiples of 128 (pad B rows); store masked to Nreal.
template<int OUT_BF16, int BIAS>
__global__ __launch_bounds__(256)
void gemm_bf16(const unsigned short* __restrict__ A, int lda,
               const unsigned short* __restrict__ B, int ldb,
               const float* __restrict__ bias,
               void* __restrict__ Cv, int ldc, int Nreal, int K) {
  __shared__ unsigned short As[128 * 32];
  __shared__ unsigned short Bs[128 * 32];
  const int tid = threadIdx.x;
  const int m0 = blockIdx.y * 128, n0 = blockIdx.x * 128;
  const int lane = tid & 63, wid = tid >> 6;
  const int wm = (wid >> 1) * 64, wn = (wid & 1) * 64;
  f32x4 acc[4][4] = {};
  const int lr = tid >> 2;               // staging row 0..63
  const int lc = (tid & 3) * 8;          // staging col (bf16 units)
  const unsigned short* Ag  = A + (size_t)(m0 + lr) * lda + lc;
  const unsigned short* Ag2 = Ag + (size_t)64 * lda;
  const unsigned short* Bg  = B + (size_t)(n0 + lr) * ldb + lc;
  const unsigned short* Bg2 = Bg + (size_t)64 * ldb;
  auto* lAs = (__attribute__((address_space(3))) char*)As;
  auto* lBs = (__attribute__((address_space(3))) char*)Bs;
  const int ldst = lr * 64 + (tid & 3) * 16;   // byte offset (row stride 64B)
  const int ar = wm + (lane & 15);
  const int br = wn + (lane & 15);
  const int kc = (lane >> 4) * 8;
  for (int k0 = 0; k0 < K; k0 += 32) {
    __builtin_amdgcn_global_load_lds((const __attribute__((address_space(1))) char*)(Ag  + k0), lAs + ldst,        16, 0, 0);
    __builtin_amdgcn_global_load_lds((const __attribute__((address_space(1))) char*)(Ag2 + k0), lAs + 4096 + ldst, 16, 0, 0);
    __builtin_amdgcn_global_load_lds((const __attribute__((address_space(1))) char*)(Bg  + k0), lBs + ldst,        16, 0, 0);
    __builtin_amdgcn_global_load_lds((const __attribute__((address_space(1))) char*)(Bg2 + k0), lBs + 4096 + ldst, 16, 0, 0);
    __syncthreads();   // drains vmcnt(0) before barrier
    s16x8 af[4], bfr[4];
#pragma unroll
    for (int i = 0; i < 4; ++i) {
      af[i]  = *(const s16x8*)&As[(ar + i * 16) * 32 + kc];
      bfr[i] = *(const s16x8*)&Bs[(br + i * 16) * 32 + kc];
    }
#pragma unroll
    for (int i = 0; i < 4; ++i)
#pragma unroll
      for (int j = 0; j < 4; ++j)
        acc[i][j] = __builtin_amdgcn_mfma_f32_16x16x32_bf16(af[i], bfr[j], acc[i][j], 0, 0, 0);
    __syncthreads();   // protect LDS before next stage
  }
  const int orow = m0 + wm + (lane >> 4) * 4;
  const int ocol = n0 + wn + (lane & 15);
#pragma unroll
  for (int j = 0; j < 4; ++j) {
    const int col = ocol + j * 16;
    if (col >= Nreal) continue;
    const float bv = BIAS ? bias[col] : 0.f;
#pragma unroll
    for (int i = 0; i < 4; ++i) {
#pragma unroll
      for (int r = 0; r < 4; ++r) {
        const int row = orow + i * 16 + r;
        const float v = acc[i][j][r] + bv;
        if (OUT_BF16) ((unsigned short*)Cv)[(size_t)row * ldc + col] = f2bf(v);
        else          ((float*)Cv)[(size_t)row * ldc + col] = v;
      }
    }
  }
}

// ================= fp32 GEMM (small, kept for h0 / base) =================
template<int ACT>  // 0 = none, 1 = tanh
__global__ __launch_bounds__(256)
void gemm_nt(const float* __restrict__ A, int lda,
             const float* __restrict__ Bt, int ldb,
             const float* __restrict__ bias,
             float* __restrict__ C, int ldc,
             int M, int N, int K) {
  __shared__ float As[16][64];
  __shared__ float Bs[16][64];
  const int tid = threadIdx.x;
  const int tx = tid & 15, ty = tid >> 4;
  const int n0 = blockIdx.x * 64, m0 = blockIdx.y * 64;
  const int lrow = tid >> 2, lkq = (tid & 3) << 2;
  const bool aval = (m0 + lrow) < M;
  const bool bval = (n0 + lrow) < N;
  const float* Ap = A  + (size_t)(m0 + lrow) * lda + lkq;
  const float* Bp = Bt + (size_t)(n0 + lrow) * ldb + lkq;
  float acc[4][4] = {};
  for (int k0 = 0; k0 < K; k0 += 16) {
    float4 av = make_float4(0.f, 0.f, 0.f, 0.f);
    float4 bv = make_float4(0.f, 0.f, 0.f, 0.f);
    if (aval) av = *(const float4*)(Ap + k0);
    if (bval) bv = *(const float4*)(Bp + k0);
    __syncthreads();
    As[lkq+0][lrow] = av.x; As[lkq+1][lrow] = av.y;
    As[lkq+2][lrow] = av.z; As[lkq+3][lrow] = av.w;
    Bs[lkq+0][lrow] = bv.x; Bs[lkq+1][lrow] = bv.y;
    Bs[lkq+2][lrow] = bv.z; Bs[lkq+3][lrow] = bv.w;
    __syncthreads();
#pragma unroll
    for (int k = 0; k < 16; ++k) {
      float a4[4], b4[4];
#pragma unroll
      for (int i = 0; i < 4; ++i) a4[i] = As[k][ty*4 + i];
#pragma unroll
      for (int j = 0; j < 4; ++j) b4[j] = Bs[k][tx*4 + j];
#pragma unroll
      for (int i = 0; i < 4; ++i)
#pragma unroll
        for (int j = 0; j < 4; ++j)
          acc[i][j] += a4[i] * b4[j];
    }
  }
#pragma unroll
  for (int i = 0; i < 4; ++i) {
    int m = m0 + ty*4 + i;
    if (m >= M) continue;
#pragma unroll
    for (int j = 0; j < 4; ++j) {
      int n = n0 + tx*4 + j;
      if (n >= N) continue;
      float v = acc[i][j];
      if (bias) v += bias[n];
      if (ACT == 1) v = tanhf(v);
      C[(size_t)m * ldc + n] = v;
    }
  }
}

// ---------------- att_feats (B,F,49) -> att_tb (B,49,F) bf16 ----------------
__global__ __launch_bounds__(256)
void transpose_att(const float* __restrict__ af, unsigned short* __restrict__ att_tb) {
  __shared__ float s[64 * NN_];
  const int b = blockIdx.y, f0 = blockIdx.x * 64;
  const float* src = af + (size_t)b * F_ * NN_ + (size_t)f0 * NN_;
  for (int i = threadIdx.x; i < 64 * NN_; i += 256) s[i] = src[i];
  __syncthreads();
  unsigned short* dst = att_tb + (size_t)b * NN_ * F_ + f0;
  for (int i = threadIdx.x; i < NN_ * 64; i += 256) {
    int n = i >> 6, j = i & 63;
    dst[(size_t)n * F_ + j] = f2bf(s[j * NN_ + n]);
  }
}

// ---------------- fp32 (strided cols) -> packed bf16 with row padding ----------------
__global__ void pack_bf16(const float* __restrict__ src, int src_ld, int c0,
                          unsigned short* __restrict__ dst, int C, int R, int Rpad) {
  int i = blockIdx.x * 256 + threadIdx.x;
  if (i >= Rpad * C) return;
  int r = i / C, c = i - r * C;
  float v = (r < R) ? src[(size_t)r * src_ld + c0 + c] : 0.f;
  dst[(size_t)r * C + c] = f2bf(v);
}

// ---------------- count-embed MLP ----------------
__global__ __launch_bounds__(128)
void count_embed_k(const float* __restrict__ cv, const float* __restrict__ w1,
                   const float* __restrict__ b1, const float* __restrict__ w2,
                   const float* __restrict__ b2, float* __restrict__ ce) {
  const int b = blockIdx.x, tid = threadIdx.x;
  __shared__ float s_cv[CV_], s_h[CD_];
  if (tid < CV_) s_cv[tid] = cv[b * CV_ + tid];
  __syncthreads();
  float acc = b1[tid];
  for (int k = 0; k < CV_; ++k) acc += s_cv[k] * w1[tid * CV_ + k];
  s_h[tid] = fmaxf(acc, 0.f);
  __syncthreads();
  float acc2 = b2[tid];
  for (int k = 0; k < CD_; ++k) acc2 += s_h[k] * w2[tid * CD_ + k];
  ce[b * CD_ + tid] = acc2;
}

// ---------------- gather word embeddings -> bf16 (B*T, E) ----------------
__global__ __launch_bounds__(128)
void gather_we(const int* __restrict__ captions, const float* __restrict__ embed_w,
               unsigned short* __restrict__ we_b) {
  const int r = blockIdx.x;           // b*T + t
  const int b = r / T_, t = r - b * T_;
  const int idx = captions[b * LCAP_ + t];
  const float4 v = ((const float4*)(embed_w + (size_t)idx * E_))[threadIdx.x];
  ushort4 o;
  o.x = f2bf(v.x); o.y = f2bf(v.y); o.z = f2bf(v.z); o.w = f2bf(v.w);
  ((ushort4*)(we_b + (size_t)r * E_))[threadIdx.x] = o;
}

__global__ void addvec_k(const float* __restrict__ a, const float* __restrict__ b,
                         float* __restrict__ o, int n) {
  int i = blockIdx.x * 256 + threadIdx.x;
  if (i < n) o[i] = a[i] + b[i];
}
__global__ void zero_k(float* __restrict__ p, int n) {
  int i = blockIdx.x * 256 + threadIdx.x;
  if (i < n) p[i] = 0.f;
}

// ================= fused per-step: lstm(t-1) + hp + scores + softmax =================
// one block per batch element b; 256 threads
__global__ __launch_bounds__(256)
void attn_lstm(const float* __restrict__ gates, float* __restrict__ c_cur,
               float* __restrict__ h_cur, unsigned short* __restrict__ H_allb,
               const float* __restrict__ att_hw, const float* __restrict__ att_hb,
               const unsigned short* __restrict__ att_projb,
               const float* __restrict__ alpha_w, const float* __restrict__ alpha_b,
               float* __restrict__ alpha, float* __restrict__ out_alpha,
               int t, int do_lstm, int do_attn) {
  const int b = blockIdx.x, tid = threadIdx.x;
  __shared__ float s_h[H_], s_hp[A_], s_aw[A_], s_sc[64];
  if (do_lstm) {
    const float* gr = gates + (size_t)b * G4_;
    for (int j = tid; j < H_; j += 256) {
      const float gi = gr[j], gf = gr[H_ + j], gg = gr[2*H_ + j], go = gr[3*H_ + j];
      const float si = 1.f / (1.f + __expf(-gi));
      const float sf = 1.f / (1.f + __expf(-gf));
      const float so = 1.f / (1.f + __expf(-go));
      const float c  = c_cur[b * H_ + j];
      const float cn = sf * c + si * tanhf(gg);
      const float hn = so * tanhf(cn);
      c_cur[b * H_ + j] = cn;
      h_cur[b * H_ + j] = hn;
      H_allb[((size_t)b * T_ + (t - 1)) * H_ + j] = f2bf(hn);
      s_h[j] = hn;
    }
  } else {
    for (int j = tid; j < H_; j += 256) s_h[j] = h_cur[b * H_ + j];
  }
  if (!do_attn) return;
  for (int a = tid; a < A_; a += 256) s_aw[a] = alpha_w[a];
  __syncthreads();
  // hp[a] = h . att_hw[a,:] + att_hb[a]   (2 a's per thread)
#pragma unroll
  for (int a2 = 0; a2 < 2; ++a2) {
    const int a = tid + a2 * 256;
    const float4* wr = (const float4*)(att_hw + (size_t)a * H_);
    float s = att_hb[a];
    for (int k = 0; k < H_ / 4; ++k) {
      const float4 w = wr[k];
      s += s_h[4*k] * w.x + s_h[4*k+1] * w.y + s_h[4*k+2] * w.z + s_h[4*k+3] * w.w;
    }
    s_hp[a] = s;
  }
  __syncthreads();
  const int wv = tid >> 6, lane = tid & 63;
  const float ab = alpha_b[0];
  for (int n = wv; n < NN_; n += 4) {
    const unsigned short* ap = att_projb + ((size_t)b * NN_ + n) * A_;
    float s = 0.f;
    for (int a = lane; a < A_; a += 64)
      s += tanhf(bf2f(ap[a]) + s_hp[a]) * s_aw[a];
#pragma unroll
    for (int off = 32; off > 0; off >>= 1) s += __shfl_down(s, off);
    if (lane == 0) s_sc[n] = s + ab;
  }
  __syncthreads();
  if (wv == 0) {
    float v = (lane < NN_) ? s_sc[lane] : -3.0e38f;
    float m = v;
#pragma unroll
    for (int off = 32; off > 0; off >>= 1) m = fmaxf(m, __shfl_xor(m, off));
    float e = (lane < NN_) ? __expf(v - m) : 0.f;
    float ssum = e;
#pragma unroll
    for (int off = 32; off > 0; off >>= 1) ssum += __shfl_xor(ssum, off);
    float a = e / ssum;
    if (lane < NN_) {
      alpha[b * NN_ + lane] = a;
      out_alpha[((size_t)b * T_ + t) * NN_ + lane] = a;
    }
  }
}

// ================= per-step gates: h@w_hh^T + alpha@attW(bf16) + base + we_proj[t] =================
__global__ __launch_bounds__(256)
void gates_step(const float* __restrict__ h_cur, const float* __restrict__ w_hh,
                const float* __restrict__ alpha, const unsigned short* __restrict__ attWb,
                const float* __restrict__ we_proj, const float* __restrict__ base,
                float* __restrict__ gates, int t) {
  __shared__ float As[16][64];
  __shared__ float Bs[16][64];
  __shared__ float s_alpha[64][NN_];
  const int tid = threadIdx.x;
  const int tx = tid & 15, ty = tid >> 4;
  const int g0 = blockIdx.x * 64, b0 = blockIdx.y * 64;
  const int lrow = tid >> 2, lkq = (tid & 3) << 2;
  float acc[4][4] = {};
  const float* Ap = h_cur + (size_t)(b0 + lrow) * H_ + lkq;
  const float* Bp = w_hh  + (size_t)(g0 + lrow) * H_ + lkq;
  for (int k0 = 0; k0 < H_; k0 += 16) {
    float4 av = *(const float4*)(Ap + k0);
    float4 bv = *(const float4*)(Bp + k0);
    __syncthreads();
    As[lkq+0][lrow] = av.x; As[lkq+1][lrow] = av.y;
    As[lkq+2][lrow] = av.z; As[lkq+3][lrow] = av.w;
    Bs[lkq+0][lrow] = bv.x; Bs[lkq+1][lrow] = bv.y;
    Bs[lkq+2][lrow] = bv.z; Bs[lkq+3][lrow] = bv.w;
    __syncthreads();
#pragma unroll
    for (int k = 0; k < 16; ++k) {
      float a4[4], b4[4];
#pragma unroll
      for (int i = 0; i < 4; ++i) a4[i] = As[k][ty*4 + i];
#pragma unroll
      for (int j = 0; j < 4; ++j) b4[j] = Bs[k][tx*4 + j];
#pragma unroll
      for (int i = 0; i < 4; ++i)
#pragma unroll
        for (int j = 0; j < 4; ++j)
          acc[i][j] += a4[i] * b4[j];
    }
  }
  __syncthreads();
  for (int i = tid; i < 64 * NN_; i += 256) {
    int bb = i / NN_, nn = i - bb * NN_;
    s_alpha[bb][nn] = alpha[(b0 + bb) * NN_ + nn];
  }
  __syncthreads();
  for (int n = 0; n < NN_; ++n) {
#pragma unroll
    for (int i = 0; i < 4; ++i) {
      const int bb = ty*4 + i;
      const float a = s_alpha[bb][n];
      const ushort4 w = *(const ushort4*)(attWb + (((size_t)(b0 + bb) * NN_ + n) << 11) + g0 + tx*4);
      acc[i][0] += a * bf2f(w.x); acc[i][1] += a * bf2f(w.y);
      acc[i][2] += a * bf2f(w.z); acc[i][3] += a * bf2f(w.w);
    }
  }
#pragma unroll
  for (int i = 0; i < 4; ++i) {
    const int b = b0 + ty*4 + i;
#pragma unroll
    for (int j = 0; j < 4; ++j) {
      const int g = g0 + tx*4 + j;
      gates[(size_t)b * G4_ + g] = acc[i][j] + base[(size_t)b * G4_ + g]
                                 + we_proj[((size_t)b * T_ + t) * G4_ + g];
    }
  }
}

extern "C" void kernel_launch(void* const* d_in, const int* in_sizes, int n_in,
                              void* d_out, int out_size, void* d_ws, size_t ws_size,
                              hipStream_t stream) {
  const float* att_feats  = (const float*)d_in[0];
  const float* fc_feats   = (const float*)d_in[1];
  const int*   captions   = (const int*)  d_in[2];
  const float* count_vecs = (const float*)d_in[3];
  const float* embed_w    = (const float*)d_in[4];
  const float* cm_w1      = (const float*)d_in[5];
  const float* cm_b1      = (const float*)d_in[6];
  const float* cm_w2      = (const float*)d_in[7];
  const float* cm_b2      = (const float*)d_in[8];
  const float* att_hw     = (const float*)d_in[9];
  const float* att_hb     = (const float*)d_in[10];
  const float* att_fw     = (const float*)d_in[11];
  const float* att_fb     = (const float*)d_in[12];
  const float* alpha_w    = (const float*)d_in[13];
  const float* alpha_b    = (const float*)d_in[14];
  const float* fcproj_w   = (const float*)d_in[15];
  const float* fcproj_b   = (const float*)d_in[16];
  const float* w_ih       = (const float*)d_in[17];
  const float* b_ih       = (const float*)d_in[18];
  const float* w_hh       = (const float*)d_in[19];
  const float* b_hh       = (const float*)d_in[20];
  const float* fc_w       = (const float*)d_in[21];
  const float* fc_b       = (const float*)d_in[22];
  float* out = (float*)d_out;

  // byte-based bump allocator on d_ws, 256B aligned
  char* wsb = (char*)d_ws;
  size_t off = 0;
  auto nxt = [&](size_t bytes) { char* p = wsb + off; off += (bytes + 255) & ~(size_t)255; return p; };
  unsigned short* att_tb    = (unsigned short*)nxt((size_t)B_*NN_*F_*2);   // 25.7MB
  unsigned short* attWb     = (unsigned short*)nxt((size_t)B_*NN_*G4_*2);  // 25.7MB
  unsigned short* att_projb = (unsigned short*)nxt((size_t)B_*NN_*A_*2);   // 6.4MB
  unsigned short* we_b      = (unsigned short*)nxt((size_t)B_*T_*E_*2);    // 3.9MB
  unsigned short* H_allb    = (unsigned short*)nxt((size_t)B_*T_*H_*2);    // 3.9MB
  unsigned short* w_ihF_b   = (unsigned short*)nxt((size_t)G4_*F_*2);      // 8.4MB
  unsigned short* w_ih0_b   = (unsigned short*)nxt((size_t)G4_*E_*2);      // 2.1MB
  unsigned short* att_fw_b  = (unsigned short*)nxt((size_t)A_*F_*2);       // 2.1MB
  unsigned short* fc_w_b    = (unsigned short*)nxt((size_t)VP_*H_*2);      // 10.4MB
  float* we_proj = (float*)nxt((size_t)B_*T_*G4_*4);                       // 31.5MB
  float* ce      = (float*)nxt((size_t)B_*CD_*4);
  float* base    = (float*)nxt((size_t)B_*G4_*4);
  float* bsum    = (float*)nxt((size_t)G4_*4);
  float* h_cur   = (float*)nxt((size_t)B_*H_*4);
  float* c_cur   = (float*)nxt((size_t)B_*H_*4);
  float* alpha   = (float*)nxt((size_t)B_*NN_*4);
  float* gates   = (float*)nxt((size_t)B_*G4_*4);
  if (off > ws_size) return;

  const size_t ALPHA_OFF = (size_t)B_ * T_ * V_;

  // ---- parallel precompute: packs + small fp32 ----
  transpose_att<<<dim3(F_/64, B_), 256, 0, stream>>>(att_feats, att_tb);
  pack_bf16<<<((size_t)G4_*F_ + 255)/256, 256, 0, stream>>>(w_ih, E_+F_+CD_, E_, w_ihF_b, F_, G4_, G4_);
  pack_bf16<<<((size_t)G4_*E_ + 255)/256, 256, 0, stream>>>(w_ih, E_+F_+CD_, 0, w_ih0_b, E_, G4_, G4_);
  pack_bf16<<<((size_t)A_*F_ + 255)/256, 256, 0, stream>>>(att_fw, F_, 0, att_fw_b, F_, A_, A_);
  pack_bf16<<<((size_t)VP_*H_ + 255)/256, 256, 0, stream>>>(fc_w, H_, 0, fc_w_b, H_, V_, VP_);
  count_embed_k<<<B_, 128, 0, stream>>>(count_vecs, cm_w1, cm_b1, cm_w2, cm_b2, ce);
  addvec_k<<<(G4_ + 255)/256, 256, 0, stream>>>(b_ih, b_hh, bsum, G4_);
  gather_we<<<B_ * T_, 128, 0, stream>>>(captions, embed_w, we_b);
  zero_k<<<(B_*H_ + 255)/256, 256, 0, stream>>>(c_cur, B_*H_);
  // h0 = tanh(fc_feats @ fcproj_w^T + b)
  gemm_nt<1><<<dim3(H_/64, B_/64), 256, 0, stream>>>(fc_feats, F_, fcproj_w, F_, fcproj_b,
                                                     h_cur, H_, B_, H_, F_);
  // base = ce @ w_ih[:, E+F:]^T + (b_ih + b_hh)
  gemm_nt<0><<<dim3(G4_/64, B_/64), 256, 0, stream>>>(ce, CD_, w_ih + E_ + F_, E_+F_+CD_,
                                                      bsum, base, G4_, B_, G4_, CD_);

  // ---- MFMA precompute GEMMs ----
  // att_proj (bf16 out): (6272 x 512, K=2048), +att_fb
  gemm_bf16<1,1><<<dim3(A_/128, (B_*NN_)/128), 256, 0, stream>>>(
      att_tb, F_, att_fw_b, F_, att_fb, att_projb, A_, A_, F_);
  // attW (bf16 out): (6272 x 2048, K=2048)
  gemm_bf16<1,0><<<dim3(G4_/128, (B_*NN_)/128), 256, 0, stream>>>(
      att_tb, F_, w_ihF_b, F_, nullptr, attWb, G4_, G4_, F_);
  // we_proj (f32 out): (3840 x 2048, K=512)
  gemm_bf16<0,0><<<dim3(G4_/128, (B_*T_)/128), 256, 0, stream>>>(
      we_b, E_, w_ih0_b, E_, nullptr, we_proj, G4_, G4_, E_);

  // ---- sequential scan: 2 kernels/step ----
  for (int t = 0; t < T_; ++t) {
    attn_lstm<<<B_, 256, 0, stream>>>(gates, c_cur, h_cur, H_allb,
                                      att_hw, att_hb, att_projb, alpha_w, alpha_b,
                                      alpha, out + ALPHA_OFF, t, (t > 0) ? 1 : 0, 1);
    gates_step<<<dim3(G4_/64, B_/64), 256, 0, stream>>>(h_cur, w_hh, alpha, attWb,
                                                        we_proj, base, gates, t);
  }
  // final lstm -> H_all[29]
  attn_lstm<<<B_, 256, 0, stream>>>(gates, c_cur, h_cur, H_allb,
                                    att_hw, att_hb, att_projb, alpha_w, alpha_b,
                                    alpha, out + ALPHA_OFF, T_, 1, 0);

  // ---- logits = H_all @ fc_w^T + fc_b -> out (B*T, V) ----
  gemm_bf16<0,1><<<dim3(VP_/128, (B_*T_)/128), 256, 0, stream>>>(
      H_allb, H_, fc_w_b, H_, fc_b, out, V_, V_, H_);
}

// Round 3
// 3231.970 us; speedup vs baseline: 1.8559x; 1.2929x over previous
//
#include <hip/hip_runtime.h>
#include <cstdint>

#define B_   128
#define T_   30
#define F_   2048
#define E_   512
#define H_   512
#define A_   512
#define CD_  128
#define CV_  64
#define V_   10000
#define VP_  10112
#define NN_  49
#define G4_  2048
#define LCAP_ 31

typedef __attribute__((ext_vector_type(4))) float f32x4;
typedef _Float16 h2v __attribute__((ext_vector_type(2)));
typedef _Float16 h4v __attribute__((ext_vector_type(4)));
typedef _Float16 h8v __attribute__((ext_vector_type(8)));

__device__ __forceinline__ float fdot2f(h2v a, h2v b, float c) {
#if __has_builtin(__builtin_amdgcn_fdot2)
  return __builtin_amdgcn_fdot2(a, b, c, false);
#else
  return c + (float)a[0]*(float)b[0] + (float)a[1]*(float)b[1];
#endif
}
__device__ __forceinline__ float dot8(h8v x, h8v w, float acc) {
  acc = fdot2f((h2v){x[0],x[1]}, (h2v){w[0],w[1]}, acc);
  acc = fdot2f((h2v){x[2],x[3]}, (h2v){w[2],w[3]}, acc);
  acc = fdot2f((h2v){x[4],x[5]}, (h2v){w[4],w[5]}, acc);
  acc = fdot2f((h2v){x[6],x[7]}, (h2v){w[6],w[7]}, acc);
  return acc;
}
__device__ __forceinline__ float tanh_f(float x) {
  x = fminf(fmaxf(x, -15.f), 15.f);
  float e = __expf(2.f * x);
  return __fdividef(e - 1.f, e + 1.f);
}
__device__ __forceinline__ float sig_f(float x) {
  return __fdividef(1.f, 1.f + __expf(-x));
}

// ================= fp16 MFMA GEMM: C = A(M,K) @ B(N,K)^T (+bias) =================
template<int OUT_H, int BIAS>
__global__ __launch_bounds__(256)
void gemm_h16(const _Float16* __restrict__ A, int lda,
              const _Float16* __restrict__ B, int ldb,
              const float* __restrict__ bias,
              void* __restrict__ Cv, int ldc, int Nreal, int K) {
  __shared__ _Float16 As[128 * 32];
  __shared__ _Float16 Bs[128 * 32];
  const int tid = threadIdx.x;
  const int m0 = blockIdx.y * 128, n0 = blockIdx.x * 128;
  const int lane = tid & 63, wid = tid >> 6;
  const int wm = (wid >> 1) * 64, wn = (wid & 1) * 64;
  f32x4 acc[4][4] = {};
  const int lr = tid >> 2;
  const int lc = (tid & 3) * 8;
  const _Float16* Ag  = A + (size_t)(m0 + lr) * lda + lc;
  const _Float16* Ag2 = Ag + (size_t)64 * lda;
  const _Float16* Bg  = B + (size_t)(n0 + lr) * ldb + lc;
  const _Float16* Bg2 = Bg + (size_t)64 * ldb;
  auto* lAs = (__attribute__((address_space(3))) char*)As;
  auto* lBs = (__attribute__((address_space(3))) char*)Bs;
  const int ldst = lr * 64 + (tid & 3) * 16;
  const int ar = wm + (lane & 15);
  const int br = wn + (lane & 15);
  const int kc = (lane >> 4) * 8;
  for (int k0 = 0; k0 < K; k0 += 32) {
    __builtin_amdgcn_global_load_lds((const __attribute__((address_space(1))) char*)(Ag  + k0), lAs + ldst,        16, 0, 0);
    __builtin_amdgcn_global_load_lds((const __attribute__((address_space(1))) char*)(Ag2 + k0), lAs + 4096 + ldst, 16, 0, 0);
    __builtin_amdgcn_global_load_lds((const __attribute__((address_space(1))) char*)(Bg  + k0), lBs + ldst,        16, 0, 0);
    __builtin_amdgcn_global_load_lds((const __attribute__((address_space(1))) char*)(Bg2 + k0), lBs + 4096 + ldst, 16, 0, 0);
    __syncthreads();
    h8v af[4], bfr[4];
#pragma unroll
    for (int i = 0; i < 4; ++i) {
      af[i]  = *(const h8v*)&As[(ar + i * 16) * 32 + kc];
      bfr[i] = *(const h8v*)&Bs[(br + i * 16) * 32 + kc];
    }
#pragma unroll
    for (int i = 0; i < 4; ++i)
#pragma unroll
      for (int j = 0; j < 4; ++j)
        acc[i][j] = __builtin_amdgcn_mfma_f32_16x16x32_f16(af[i], bfr[j], acc[i][j], 0, 0, 0);
    __syncthreads();
  }
  const int orow = m0 + wm + (lane >> 4) * 4;
  const int ocol = n0 + wn + (lane & 15);
#pragma unroll
  for (int j = 0; j < 4; ++j) {
    const int col = ocol + j * 16;
    if (col >= Nreal) continue;
    const float bv = BIAS ? bias[col] : 0.f;
#pragma unroll
    for (int i = 0; i < 4; ++i) {
#pragma unroll
      for (int r = 0; r < 4; ++r) {
        const int row = orow + i * 16 + r;
        const float v = acc[i][j][r] + bv;
        if (OUT_H) ((_Float16*)Cv)[(size_t)row * ldc + col] = (_Float16)v;
        else       ((float*)Cv)[(size_t)row * ldc + col] = v;
      }
    }
  }
}

// ---------------- att_feats (B,F,49) -> att_th (B,49,F) fp16 ----------------
__global__ __launch_bounds__(256)
void transpose_att(const float* __restrict__ af, _Float16* __restrict__ att_th) {
  __shared__ float s[64 * NN_];
  const int b = blockIdx.y, f0 = blockIdx.x * 64;
  const float* src = af + (size_t)b * F_ * NN_ + (size_t)f0 * NN_;
  for (int i = threadIdx.x; i < 64 * NN_; i += 256) s[i] = src[i];
  __syncthreads();
  _Float16* dst = att_th + (size_t)b * NN_ * F_ + f0;
  for (int i = threadIdx.x; i < NN_ * 64; i += 256) {
    int n = i >> 6, j = i & 63;
    dst[(size_t)n * F_ + j] = (_Float16)s[j * NN_ + n];
  }
}

// ---------------- generic fp32 -> fp16 pack (optional gate-permuted rows, row pad) ----------------
template<int PERM>
__global__ void pack_h16(const float* __restrict__ src, int src_ld, int c0,
                         _Float16* __restrict__ dst, int C, int R, int Rpad) {
  int i = blockIdx.x * 256 + threadIdx.x;
  if (i >= Rpad * C) return;
  int r = i / C, c = i - r * C;
  int row = PERM ? ((r & 3) * 512 + (r >> 2)) : r;
  float v = (r < R) ? src[(size_t)row * src_ld + c0 + c] : 0.f;
  dst[i] = (_Float16)v;
}

// ---------------- fp32 -> fp16 k-interleaved pack: dst[(k/8)*R*8 + r*8 + k%8] ----------------
template<int PERM>
__global__ void pack_ki8(const float* __restrict__ src, int src_ld, int c0,
                         _Float16* __restrict__ dst, int R, int K) {
  int i = blockIdx.x * 256 + threadIdx.x;
  if (i >= R * K) return;
  int k7 = i & 7;
  int t = i >> 3;
  int r = t & (R - 1);      // R is power of two (512 or 2048)
  int kb = t / R;
  int k = kb * 8 + k7;
  int row = PERM ? ((r & 3) * 512 + (r >> 2)) : r;
  dst[i] = (_Float16)src[(size_t)row * src_ld + c0 + k];
}

// ---------------- count-embed MLP (fp32) ----------------
__global__ __launch_bounds__(128)
void count_embed_k(const float* __restrict__ cv, const float* __restrict__ w1,
                   const float* __restrict__ b1, const float* __restrict__ w2,
                   const float* __restrict__ b2, float* __restrict__ ce) {
  const int b = blockIdx.x, tid = threadIdx.x;
  __shared__ float s_cv[CV_], s_h[CD_];
  if (tid < CV_) s_cv[tid] = cv[b * CV_ + tid];
  __syncthreads();
  float acc = b1[tid];
  for (int k = 0; k < CV_; ++k) acc += s_cv[k] * w1[tid * CV_ + k];
  s_h[tid] = fmaxf(acc, 0.f);
  __syncthreads();
  float acc2 = b2[tid];
  for (int k = 0; k < CD_; ++k) acc2 += s_h[k] * w2[tid * CD_ + k];
  ce[b * CD_ + tid] = acc2;
}

// ---------------- gather word embeddings -> fp16 (B*T, E) ----------------
__global__ __launch_bounds__(128)
void gather_we(const int* __restrict__ captions, const float* __restrict__ embed_w,
               _Float16* __restrict__ we_h) {
  const int r = blockIdx.x;
  const int b = r / T_, t = r - b * T_;
  const int idx = captions[b * LCAP_ + t];
  const float4 v = ((const float4*)(embed_w + (size_t)idx * E_))[threadIdx.x];
  h4v o = { (_Float16)v.x, (_Float16)v.y, (_Float16)v.z, (_Float16)v.w };
  ((h4v*)(we_h + (size_t)r * E_))[threadIdx.x] = o;
}

// ================= persistent per-batch sequential loop =================
// 128 blocks (one per b) x 512 threads. Runs h0, base, and all 30 steps.
__global__ __launch_bounds__(512)
void seq_loop(const _Float16* __restrict__ fcfeat_h,   // B x F
              const _Float16* __restrict__ fcproj_k,   // ki8 R=512 K=F
              const float* __restrict__ fcproj_b,
              const _Float16* __restrict__ wcnt_h,     // perm rows 2048 x CD
              const float* __restrict__ ce,            // B x CD f32
              const float* __restrict__ b_ih, const float* __restrict__ b_hh,
              const _Float16* __restrict__ atthw_k,    // ki8 R=512 K=512
              const float* __restrict__ att_hb,
              const _Float16* __restrict__ attproj_h,  // B x 49 x 512
              const float* __restrict__ alpha_w, const float* __restrict__ alpha_b,
              const _Float16* __restrict__ attW_h,     // B x 49 x 2048 (perm p)
              const float* __restrict__ we_proj,       // (B*T) x 2048 (perm p) f32
              const _Float16* __restrict__ whh_k,      // ki8 R=2048(perm) K=512
              _Float16* __restrict__ H_all_h,          // (B*T) x 512
              float* __restrict__ out_alpha) {         // B x T x 49
  const int b = blockIdx.x, tid = threadIdx.x;
  __shared__ _Float16 s_h[H_];
  __shared__ _Float16 s_x[F_];
  __shared__ _Float16 s_ceh[CD_];
  __shared__ float s_hp[A_], s_aw[A_];
  __shared__ float s_sc[64], s_alpha[64];

  // ---- prologue ----
  s_aw[tid] = alpha_w[tid];
  const float ahb = att_hb[tid];
  const float ab  = alpha_b[0];
  if (tid < CD_) s_ceh[tid] = (_Float16)ce[b * CD_ + tid];
  ((ushort4*)s_x)[tid] = ((const ushort4*)(fcfeat_h + (size_t)b * F_))[tid];
  __syncthreads();

  float c_state = 0.f;
  {  // h0[j=tid] = tanh(fc_feats[b] . fcproj[j] + fcproj_b[j])
    float acc = fcproj_b[tid];
    const h8v* xv = (const h8v*)s_x;
    const h8v* wp = (const h8v*)fcproj_k;
    for (int k8 = 0; k8 < F_ / 8; ++k8)
      acc = dot8(xv[k8], wp[(size_t)k8 * 512 + tid], acc);
    s_h[tid] = (_Float16)tanh_f(acc);
  }
  float base_r[4];
  {  // base[p=4*tid+r] = b_ih[g] + b_hh[g] + ce . wcnt[p]   (g = r*512 + tid)
    const h8v* cv = (const h8v*)s_ceh;
#pragma unroll
    for (int r = 0; r < 4; ++r) {
      const int p = 4 * tid + r;
      float acc = b_ih[r * 512 + tid] + b_hh[r * 512 + tid];
      const h8v* wr = (const h8v*)(wcnt_h + (size_t)p * CD_);
#pragma unroll
      for (int k8 = 0; k8 < CD_ / 8; ++k8)
        acc = dot8(cv[k8], wr[k8], acc);
      base_r[r] = acc;
    }
  }
  __syncthreads();

  const _Float16* apb = attproj_h + (size_t)b * NN_ * A_;
  const _Float16* aWb = attW_h + (size_t)b * NN_ * G4_;
  const int wv_ = tid >> 6, lane = tid & 63;

  for (int t = 0; t < T_; ++t) {
    // ---- A: hp[a=tid] = att_hb[a] + h . att_hw[a] ----
    {
      float acc = ahb;
      const h8v* hv = (const h8v*)s_h;
      const h8v* wp = (const h8v*)atthw_k;
      for (int k8 = 0; k8 < H_ / 8; ++k8)
        acc = dot8(hv[k8], wp[(size_t)k8 * 512 + tid], acc);
      s_hp[tid] = acc;
    }
    __syncthreads();
    // ---- B: scores[n] = sum_a tanh(att_proj + hp) * aw ----
    for (int n = wv_; n < NN_; n += 8) {
      const _Float16* ap = apb + (size_t)n * A_;
      float s = 0.f;
#pragma unroll
      for (int i = 0; i < 8; ++i) {
        const int a = lane + 64 * i;
        const float x = (float)ap[a] + s_hp[a];
        const float e = __expf(2.f * fminf(fmaxf(x, -15.f), 15.f));
        s += __fdividef(e - 1.f, e + 1.f) * s_aw[a];
      }
#pragma unroll
      for (int off = 32; off > 0; off >>= 1) s += __shfl_xor(s, off);
      if (lane == 0) s_sc[n] = s + ab;
    }
    __syncthreads();
    // ---- C: softmax over 49 (wave 0) ----
    if (wv_ == 0) {
      float v = (lane < NN_) ? s_sc[lane] : -3.0e38f;
      float m = v;
#pragma unroll
      for (int off = 32; off > 0; off >>= 1) m = fmaxf(m, __shfl_xor(m, off));
      float e = (lane < NN_) ? __expf(v - m) : 0.f;
      float ssum = e;
#pragma unroll
      for (int off = 32; off > 0; off >>= 1) ssum += __shfl_xor(ssum, off);
      const float a = __fdividef(e, ssum);
      if (lane < NN_) {
        s_alpha[lane] = a;
        out_alpha[((size_t)b * T_ + t) * NN_ + lane] = a;
      }
    }
    __syncthreads();
    // ---- D: gates + LSTM (thread owns j=tid; p = 4*tid + r) ----
    float acc[4];
    {
      const float4 wp4 = *(const float4*)(we_proj + ((size_t)b * T_ + t) * G4_ + 4 * tid);
      acc[0] = base_r[0] + wp4.x; acc[1] = base_r[1] + wp4.y;
      acc[2] = base_r[2] + wp4.z; acc[3] = base_r[3] + wp4.w;
      for (int n = 0; n < NN_; ++n) {
        const float al = s_alpha[n];
        const h4v w = *(const h4v*)(aWb + (size_t)n * G4_ + 4 * tid);
        acc[0] += al * (float)w[0]; acc[1] += al * (float)w[1];
        acc[2] += al * (float)w[2]; acc[3] += al * (float)w[3];
      }
      const h8v* hv = (const h8v*)s_h;
#pragma unroll 2
      for (int k8 = 0; k8 < H_ / 8; ++k8) {
        const h8v x = hv[k8];
        const h8v* wr = (const h8v*)whh_k + (size_t)k8 * G4_ + 4 * tid;
        acc[0] = dot8(x, wr[0], acc[0]);
        acc[1] = dot8(x, wr[1], acc[1]);
        acc[2] = dot8(x, wr[2], acc[2]);
        acc[3] = dot8(x, wr[3], acc[3]);
      }
    }
    const float si = sig_f(acc[0]), sf = sig_f(acc[1]), so = sig_f(acc[3]);
    c_state = sf * c_state + si * tanh_f(acc[2]);
    const float hn = so * tanh_f(c_state);
    __syncthreads();   // all reads of s_h done before overwrite
    s_h[tid] = (_Float16)hn;
    H_all_h[((size_t)b * T_ + t) * H_ + tid] = (_Float16)hn;
    __syncthreads();   // s_h ready for next step's hp
  }
}

extern "C" void kernel_launch(void* const* d_in, const int* in_sizes, int n_in,
                              void* d_out, int out_size, void* d_ws, size_t ws_size,
                              hipStream_t stream) {
  const float* att_feats  = (const float*)d_in[0];
  const float* fc_feats   = (const float*)d_in[1];
  const int*   captions   = (const int*)  d_in[2];
  const float* count_vecs = (const float*)d_in[3];
  const float* embed_w    = (const float*)d_in[4];
  const float* cm_w1      = (const float*)d_in[5];
  const float* cm_b1      = (const float*)d_in[6];
  const float* cm_w2      = (const float*)d_in[7];
  const float* cm_b2      = (const float*)d_in[8];
  const float* att_hw     = (const float*)d_in[9];
  const float* att_hb     = (const float*)d_in[10];
  const float* att_fw     = (const float*)d_in[11];
  const float* att_fb     = (const float*)d_in[12];
  const float* alpha_w    = (const float*)d_in[13];
  const float* alpha_b    = (const float*)d_in[14];
  const float* fcproj_w   = (const float*)d_in[15];
  const float* fcproj_b   = (const float*)d_in[16];
  const float* w_ih       = (const float*)d_in[17];
  const float* b_ih       = (const float*)d_in[18];
  const float* w_hh       = (const float*)d_in[19];
  const float* b_hh       = (const float*)d_in[20];
  const float* fc_w       = (const float*)d_in[21];
  const float* fc_b       = (const float*)d_in[22];
  float* out = (float*)d_out;

  char* wsb = (char*)d_ws;
  size_t off = 0;
  auto nxt = [&](size_t bytes) { char* p = wsb + off; off += (bytes + 255) & ~(size_t)255; return p; };
  _Float16* att_th    = (_Float16*)nxt((size_t)B_*NN_*F_*2);
  _Float16* attW_h    = (_Float16*)nxt((size_t)B_*NN_*G4_*2);
  _Float16* attproj_h = (_Float16*)nxt((size_t)B_*NN_*A_*2);
  _Float16* we_h      = (_Float16*)nxt((size_t)B_*T_*E_*2);
  _Float16* H_all_h   = (_Float16*)nxt((size_t)B_*T_*H_*2);
  _Float16* w_ihF_h   = (_Float16*)nxt((size_t)G4_*F_*2);
  _Float16* w_ih0_h   = (_Float16*)nxt((size_t)G4_*E_*2);
  _Float16* wcnt_h    = (_Float16*)nxt((size_t)G4_*CD_*2);
  _Float16* fc_w_h    = (_Float16*)nxt((size_t)VP_*H_*2);
  _Float16* att_fw_h  = (_Float16*)nxt((size_t)A_*F_*2);
  _Float16* fcfeat_h  = (_Float16*)nxt((size_t)B_*F_*2);
  _Float16* whh_k     = (_Float16*)nxt((size_t)G4_*H_*2);
  _Float16* atthw_k   = (_Float16*)nxt((size_t)A_*H_*2);
  _Float16* fcproj_k  = (_Float16*)nxt((size_t)H_*F_*2);
  float*    we_proj   = (float*)nxt((size_t)B_*T_*G4_*4);
  float*    ce        = (float*)nxt((size_t)B_*CD_*4);
  if (off > ws_size) return;

  const size_t ALPHA_OFF = (size_t)B_ * T_ * V_;

  // ---- packs & small precompute ----
  transpose_att<<<dim3(F_/64, B_), 256, 0, stream>>>(att_feats, att_th);
  pack_h16<0><<<((size_t)B_*F_ + 255)/256, 256, 0, stream>>>(fc_feats, F_, 0, fcfeat_h, F_, B_, B_);
  pack_h16<1><<<((size_t)G4_*F_ + 255)/256, 256, 0, stream>>>(w_ih, E_+F_+CD_, E_, w_ihF_h, F_, G4_, G4_);
  pack_h16<1><<<((size_t)G4_*E_ + 255)/256, 256, 0, stream>>>(w_ih, E_+F_+CD_, 0, w_ih0_h, E_, G4_, G4_);
  pack_h16<1><<<((size_t)G4_*CD_ + 255)/256, 256, 0, stream>>>(w_ih, E_+F_+CD_, E_+F_, wcnt_h, CD_, G4_, G4_);
  pack_h16<0><<<((size_t)A_*F_ + 255)/256, 256, 0, stream>>>(att_fw, F_, 0, att_fw_h, F_, A_, A_);
  pack_h16<0><<<((size_t)VP_*H_ + 255)/256, 256, 0, stream>>>(fc_w, H_, 0, fc_w_h, H_, V_, VP_);
  pack_ki8<1><<<((size_t)G4_*H_ + 255)/256, 256, 0, stream>>>(w_hh, H_, 0, whh_k, G4_, H_);
  pack_ki8<0><<<((size_t)A_*H_ + 255)/256, 256, 0, stream>>>(att_hw, H_, 0, atthw_k, A_, H_);
  pack_ki8<0><<<((size_t)H_*F_ + 255)/256, 256, 0, stream>>>(fcproj_w, F_, 0, fcproj_k, H_, F_);
  count_embed_k<<<B_, 128, 0, stream>>>(count_vecs, cm_w1, cm_b1, cm_w2, cm_b2, ce);
  gather_we<<<B_ * T_, 128, 0, stream>>>(captions, embed_w, we_h);

  // ---- MFMA precompute GEMMs ----
  gemm_h16<1,1><<<dim3(A_/128, (B_*NN_)/128), 256, 0, stream>>>(
      att_th, F_, att_fw_h, F_, att_fb, attproj_h, A_, A_, F_);
  gemm_h16<1,0><<<dim3(G4_/128, (B_*NN_)/128), 256, 0, stream>>>(
      att_th, F_, w_ihF_h, F_, nullptr, attW_h, G4_, G4_, F_);
  gemm_h16<0,0><<<dim3(G4_/128, (B_*T_)/128), 256, 0, stream>>>(
      we_h, E_, w_ih0_h, E_, nullptr, we_proj, G4_, G4_, E_);

  // ---- persistent sequential loop (one block per batch element) ----
  seq_loop<<<B_, 512, 0, stream>>>(fcfeat_h, fcproj_k, fcproj_b,
                                   wcnt_h, ce, b_ih, b_hh,
                                   atthw_k, att_hb,
                                   attproj_h, alpha_w, alpha_b,
                                   attW_h, we_proj, whh_k,
                                   H_all_h, out + ALPHA_OFF);

  // ---- logits = H_all @ fc_w^T + fc_b -> out (B*T, V) ----
  gemm_h16<0,1><<<dim3(VP_/128, (B_*T_)/128), 256, 0, stream>>>(
      H_all_h, H_, fc_w_h, H_, fc_b, out, V_, V_, H_);
}

// Round 4
// 1841.727 us; speedup vs baseline: 3.2568x; 1.7549x over previous
//
#include <hip/hip_runtime.h>
#include <cstdint>

#define B_   128
#define T_   30
#define F_   2048
#define E_   512
#define H_   512
#define A_   512
#define CD_  128
#define CV_  64
#define V_   10000
#define VP_  10112
#define NN_  49
#define G4_  2048
#define LCAP_ 31

typedef __attribute__((ext_vector_type(4))) float f32x4;
typedef _Float16 h2v __attribute__((ext_vector_type(2)));
typedef _Float16 h4v __attribute__((ext_vector_type(4)));
typedef _Float16 h8v __attribute__((ext_vector_type(8)));

__device__ __forceinline__ float fdot2f(h2v a, h2v b, float c) {
#if __has_builtin(__builtin_amdgcn_fdot2)
  return __builtin_amdgcn_fdot2(a, b, c, false);
#else
  return c + (float)a[0]*(float)b[0] + (float)a[1]*(float)b[1];
#endif
}
__device__ __forceinline__ float dot8(h8v x, h8v w, float acc) {
  acc = fdot2f((h2v){x[0],x[1]}, (h2v){w[0],w[1]}, acc);
  acc = fdot2f((h2v){x[2],x[3]}, (h2v){w[2],w[3]}, acc);
  acc = fdot2f((h2v){x[4],x[5]}, (h2v){w[4],w[5]}, acc);
  acc = fdot2f((h2v){x[6],x[7]}, (h2v){w[6],w[7]}, acc);
  return acc;
}
__device__ __forceinline__ float tanh_f(float x) {
  x = fminf(fmaxf(x, -15.f), 15.f);
  float e = __expf(2.f * x);
  return __fdividef(e - 1.f, e + 1.f);
}
__device__ __forceinline__ float sig_f(float x) {
  return __fdividef(1.f, 1.f + __expf(-x));
}

// ================= fp16 MFMA GEMM: C = A(M,K) @ B(N,K)^T (+bias) =================
template<int OUT_H, int BIAS>
__global__ __launch_bounds__(256)
void gemm_h16(const _Float16* __restrict__ A, int lda,
              const _Float16* __restrict__ B, int ldb,
              const float* __restrict__ bias,
              void* __restrict__ Cv, int ldc, int Nreal, int K) {
  __shared__ _Float16 As[128 * 32];
  __shared__ _Float16 Bs[128 * 32];
  const int tid = threadIdx.x;
  const int m0 = blockIdx.y * 128, n0 = blockIdx.x * 128;
  const int lane = tid & 63, wid = tid >> 6;
  const int wm = (wid >> 1) * 64, wn = (wid & 1) * 64;
  f32x4 acc[4][4] = {};
  const int lr = tid >> 2;
  const int lc = (tid & 3) * 8;
  const _Float16* Ag  = A + (size_t)(m0 + lr) * lda + lc;
  const _Float16* Ag2 = Ag + (size_t)64 * lda;
  const _Float16* Bg  = B + (size_t)(n0 + lr) * ldb + lc;
  const _Float16* Bg2 = Bg + (size_t)64 * ldb;
  auto* lAs = (__attribute__((address_space(3))) char*)As;
  auto* lBs = (__attribute__((address_space(3))) char*)Bs;
  const int ldst = lr * 64 + (tid & 3) * 16;
  const int ar = wm + (lane & 15);
  const int br = wn + (lane & 15);
  const int kc = (lane >> 4) * 8;
  for (int k0 = 0; k0 < K; k0 += 32) {
    __builtin_amdgcn_global_load_lds((const __attribute__((address_space(1))) char*)(Ag  + k0), lAs + ldst,        16, 0, 0);
    __builtin_amdgcn_global_load_lds((const __attribute__((address_space(1))) char*)(Ag2 + k0), lAs + 4096 + ldst, 16, 0, 0);
    __builtin_amdgcn_global_load_lds((const __attribute__((address_space(1))) char*)(Bg  + k0), lBs + ldst,        16, 0, 0);
    __builtin_amdgcn_global_load_lds((const __attribute__((address_space(1))) char*)(Bg2 + k0), lBs + 4096 + ldst, 16, 0, 0);
    __syncthreads();
    h8v af[4], bfr[4];
#pragma unroll
    for (int i = 0; i < 4; ++i) {
      af[i]  = *(const h8v*)&As[(ar + i * 16) * 32 + kc];
      bfr[i] = *(const h8v*)&Bs[(br + i * 16) * 32 + kc];
    }
#pragma unroll
    for (int i = 0; i < 4; ++i)
#pragma unroll
      for (int j = 0; j < 4; ++j)
        acc[i][j] = __builtin_amdgcn_mfma_f32_16x16x32_f16(af[i], bfr[j], acc[i][j], 0, 0, 0);
    __syncthreads();
  }
  const int orow = m0 + wm + (lane >> 4) * 4;
  const int ocol = n0 + wn + (lane & 15);
#pragma unroll
  for (int j = 0; j < 4; ++j) {
    const int col = ocol + j * 16;
    if (col >= Nreal) continue;
    const float bv = BIAS ? bias[col] : 0.f;
#pragma unroll
    for (int i = 0; i < 4; ++i) {
#pragma unroll
      for (int r = 0; r < 4; ++r) {
        const int row = orow + i * 16 + r;
        const float v = acc[i][j][r] + bv;
        if (OUT_H) ((_Float16*)Cv)[(size_t)row * ldc + col] = (_Float16)v;
        else       ((float*)Cv)[(size_t)row * ldc + col] = v;
      }
    }
  }
}

// ---------------- att_feats (B,F,49) -> att_th (B,49,F) fp16 ----------------
__global__ __launch_bounds__(256)
void transpose_att(const float* __restrict__ af, _Float16* __restrict__ att_th) {
  __shared__ float s[64 * NN_];
  const int b = blockIdx.y, f0 = blockIdx.x * 64;
  const float* src = af + (size_t)b * F_ * NN_ + (size_t)f0 * NN_;
  for (int i = threadIdx.x; i < 64 * NN_; i += 256) s[i] = src[i];
  __syncthreads();
  _Float16* dst = att_th + (size_t)b * NN_ * F_ + f0;
  for (int i = threadIdx.x; i < NN_ * 64; i += 256) {
    int n = i >> 6, j = i & 63;
    dst[(size_t)n * F_ + j] = (_Float16)s[j * NN_ + n];
  }
}

// ---------------- fp32 (strided cols) -> packed fp16, row pad ----------------
__global__ void pack_h16(const float* __restrict__ src, int src_ld, int c0,
                         _Float16* __restrict__ dst, int C, int R, int Rpad) {
  int i = blockIdx.x * 256 + threadIdx.x;
  if (i >= Rpad * C) return;
  int r = i / C, c = i - r * C;
  float v = (r < R) ? src[(size_t)r * src_ld + c0 + c] : 0.f;
  dst[i] = (_Float16)v;
}

// ---------------- fp32 -> fp16 k-interleaved: dst[(k/8)*R*8 + r*8 + k%8] ----------------
__global__ void pack_ki8(const float* __restrict__ src, int src_ld, int c0,
                         _Float16* __restrict__ dst, int R, int K) {
  int i = blockIdx.x * 256 + threadIdx.x;
  if (i >= R * K) return;
  int k7 = i & 7;
  int t = i >> 3;
  int r = t & (R - 1);      // R power of two
  int kb = t / R;
  int k = kb * 8 + k7;
  dst[i] = (_Float16)src[(size_t)r * src_ld + c0 + k];
}

// ---------------- count-embed MLP (fp32) ----------------
__global__ __launch_bounds__(128)
void count_embed_k(const float* __restrict__ cv, const float* __restrict__ w1,
                   const float* __restrict__ b1, const float* __restrict__ w2,
                   const float* __restrict__ b2, float* __restrict__ ce) {
  const int b = blockIdx.x, tid = threadIdx.x;
  __shared__ float s_cv[CV_], s_h[CD_];
  if (tid < CV_) s_cv[tid] = cv[b * CV_ + tid];
  __syncthreads();
  float acc = b1[tid];
  for (int k = 0; k < CV_; ++k) acc += s_cv[k] * w1[tid * CV_ + k];
  s_h[tid] = fmaxf(acc, 0.f);
  __syncthreads();
  float acc2 = b2[tid];
  for (int k = 0; k < CD_; ++k) acc2 += s_h[k] * w2[tid * CD_ + k];
  ce[b * CD_ + tid] = acc2;
}

// ---------------- gather word embeddings -> fp16 (B*T, E) ----------------
__global__ __launch_bounds__(128)
void gather_we(const int* __restrict__ captions, const float* __restrict__ embed_w,
               _Float16* __restrict__ we_h) {
  const int r = blockIdx.x;
  const int b = r / T_, t = r - b * T_;
  const int idx = captions[b * LCAP_ + t];
  const float4 v = ((const float4*)(embed_w + (size_t)idx * E_))[threadIdx.x];
  h4v o = { (_Float16)v.x, (_Float16)v.y, (_Float16)v.z, (_Float16)v.w };
  ((h4v*)(we_h + (size_t)r * E_))[threadIdx.x] = o;
}

// ================= persistent per-batch sequential loop =================
// 128 blocks (one per b) x 1024 threads.
// attproj[b] lives in LDS (50KB, loaded once); attW[b] columns live in registers
// (each thread owns gate pair p = {2tid, 2tid+1}); whh/atthw stream from L2.
__global__ __launch_bounds__(1024)
void seq_loop(const _Float16* __restrict__ fcfeat_h,   // B x F
              const _Float16* __restrict__ fcproj_k,   // ki8 R=512 K=F
              const float* __restrict__ fcproj_b,
              const _Float16* __restrict__ wcnt_h,     // 2048 x CD
              const float* __restrict__ ce,            // B x CD f32
              const float* __restrict__ b_ih, const float* __restrict__ b_hh,
              const _Float16* __restrict__ atthw_k,    // ki8 R=512 K=512
              const float* __restrict__ att_hb,
              const _Float16* __restrict__ attproj_h,  // B x 49 x 512
              const float* __restrict__ alpha_w, const float* __restrict__ alpha_b,
              const _Float16* __restrict__ attW_h,     // B x 49 x 2048
              const float* __restrict__ we_proj,       // (B*T) x 2048 f32
              const _Float16* __restrict__ whh_k,      // ki8 R=2048 K=512
              _Float16* __restrict__ H_all_h,          // (B*T) x 512
              float* __restrict__ out_alpha) {         // B x T x 49
  const int b = blockIdx.x, tid = threadIdx.x;
  __shared__ _Float16 s_ap[NN_ * A_];      // 50 KB: attproj[b] (+att_fb)
  __shared__ _Float16 s_h[H_];             // 1 KB
  __shared__ float    s_hp2[2][A_];        // 4 KB
  __shared__ _Float16 s_gates[G4_];        // 4 KB (fp16 gate pre-acts; prologue: fcfeat)
  __shared__ float    s_sc[64];
  __shared__ float    s_alpha[64];
  __shared__ float    s_ce[CD_];

  const int a9 = tid & 511, half = tid >> 9;
  const int wv = tid >> 6, lane = tid & 63;

  // ---- prologue: fill LDS ----
  // fcfeat (2048 halves) into s_gates area (4 KB)
  ((uint*)s_gates)[tid] = ((const uint*)(fcfeat_h + (size_t)b * F_))[tid];
  // attproj[b]: 49*512 halves = 12544 uints
  {
    const uint* src = (const uint*)(attproj_h + (size_t)b * NN_ * A_);
    for (int i = tid; i < NN_ * A_ / 2; i += 1024) ((uint*)s_ap)[i] = src[i];
  }
  if (tid < CD_) s_ce[tid] = ce[b * CD_ + tid];
  // attW columns for this thread's gate pair -> registers
  h2v aW[NN_];
  {
    const _Float16* base = attW_h + (size_t)b * NN_ * G4_ + 2 * tid;
#pragma unroll
    for (int n = 0; n < NN_; ++n) aW[n] = *(const h2v*)(base + (size_t)n * G4_);
  }
  float aw8[8];
#pragma unroll
  for (int i = 0; i < 8; ++i) aw8[i] = alpha_w[lane * 8 + i];
  const float ab  = alpha_b[0];
  const float ahb = (half == 0) ? att_hb[a9] : 0.f;
  __syncthreads();

  // h0 (threads 0..511): tanh(fcfeat . fcproj + b)
  float c_state = 0.f;
  if (tid < H_) {
    float acc = fcproj_b[tid];
    const h8v* xv = (const h8v*)s_gates;   // fcfeat lives here
    const h8v* wp = (const h8v*)fcproj_k;
    for (int k8 = 0; k8 < F_ / 8; ++k8)
      acc = dot8(xv[k8], wp[(size_t)k8 * 512 + tid], acc);
    s_h[tid] = (_Float16)tanh_f(acc);
  }
  // base for gate pair p = {2tid, 2tid+1}: b_ih + b_hh + ce . wcnt[p]
  float base0 = b_ih[2 * tid]     + b_hh[2 * tid];
  float base1 = b_ih[2 * tid + 1] + b_hh[2 * tid + 1];
  {
    const h8v* w0 = (const h8v*)(wcnt_h + (size_t)(2 * tid) * CD_);
    const h8v* w1 = (const h8v*)(wcnt_h + (size_t)(2 * tid + 1) * CD_);
#pragma unroll
    for (int k8 = 0; k8 < CD_ / 8; ++k8) {
      const h8v a = w0[k8], c = w1[k8];
#pragma unroll
      for (int i = 0; i < 8; ++i) {
        const float cv = s_ce[k8 * 8 + i];
        base0 += cv * (float)a[i];
        base1 += cv * (float)c[i];
      }
    }
  }
  __syncthreads();   // s_h ready; fcfeat area free for gates

  const h8v* atthw8 = (const h8v*)atthw_k;
  const h8v* whh8   = (const h8v*)whh_k;

  for (int t = 0; t < T_; ++t) {
    // ---- A: hp[a] = att_hb[a] + h . att_hw[a]  (split K across halves) ----
    {
      float acc = ahb;
      const h8v* hv = (const h8v*)s_h;
      const int k80 = half * 32;
#pragma unroll 8
      for (int k8 = k80; k8 < k80 + 32; ++k8)
        acc = dot8(hv[k8], atthw8[(size_t)k8 * 512 + a9], acc);
      s_hp2[half][a9] = acc;
    }
    __syncthreads();
    // ---- B: scores[n] = sum_a tanh(attproj[n][a] + hp[a]) * aw[a] ----
    {
      float hp8[8];
#pragma unroll
      for (int i = 0; i < 8; ++i) {
        const int a = lane * 8 + i;
        hp8[i] = s_hp2[0][a] + s_hp2[1][a];
      }
      const int Q = (wv == 0) ? 4 : 3;
      for (int q = 0; q < Q; ++q) {
        const int n = wv + 16 * q;
        const h8v apv = *(const h8v*)&s_ap[n * A_ + lane * 8];
        float s = 0.f;
#pragma unroll
        for (int i = 0; i < 8; ++i) {
          const float x = (float)apv[i] + hp8[i];
          const float e = __expf(2.f * fminf(fmaxf(x, -15.f), 15.f));
          s += __fdividef(e - 1.f, e + 1.f) * aw8[i];
        }
#pragma unroll
        for (int off = 32; off > 0; off >>= 1) s += __shfl_xor(s, off);
        if (lane == 0) s_sc[n] = s + ab;
      }
    }
    __syncthreads();
    // ---- C: softmax over 49 (wave 0) ----
    if (wv == 0) {
      float v = (lane < NN_) ? s_sc[lane] : -3.0e38f;
      float m = v;
#pragma unroll
      for (int off = 32; off > 0; off >>= 1) m = fmaxf(m, __shfl_xor(m, off));
      float e = (lane < NN_) ? __expf(v - m) : 0.f;
      float ssum = e;
#pragma unroll
      for (int off = 32; off > 0; off >>= 1) ssum += __shfl_xor(ssum, off);
      const float a = __fdividef(e, ssum);
      if (lane < NN_) {
        s_alpha[lane] = a;
        out_alpha[((size_t)b * T_ + t) * NN_ + lane] = a;
      }
    }
    __syncthreads();
    // ---- D: gate pair = base + we_proj + alpha@attW(reg) + h@whh(L2 stream) ----
    {
      const float2 wp = *(const float2*)(we_proj + ((size_t)b * T_ + t) * G4_ + 2 * tid);
      float acc0 = base0 + wp.x, acc1 = base1 + wp.y;
#pragma unroll
      for (int n = 0; n < NN_; ++n) {
        const float al = s_alpha[n];
        acc0 += al * (float)aW[n][0];
        acc1 += al * (float)aW[n][1];
      }
      const h8v* hv = (const h8v*)s_h;
#pragma unroll 4
      for (int k8 = 0; k8 < H_ / 8; ++k8) {
        const h8v x = hv[k8];
        acc0 = dot8(x, whh8[(size_t)k8 * G4_ + 2 * tid],     acc0);
        acc1 = dot8(x, whh8[(size_t)k8 * G4_ + 2 * tid + 1], acc1);
      }
      *(h2v*)&s_gates[2 * tid] = (h2v){ (_Float16)acc0, (_Float16)acc1 };
    }
    __syncthreads();
    // ---- E: LSTM cell (threads 0..511) ----
    if (tid < H_) {
      const int j = tid;
      const float gi = (float)s_gates[j];
      const float gf = (float)s_gates[512 + j];
      const float gg = (float)s_gates[1024 + j];
      const float go = (float)s_gates[1536 + j];
      const float si = sig_f(gi), sf = sig_f(gf), so = sig_f(go);
      c_state = sf * c_state + si * tanh_f(gg);
      const float hn = so * tanh_f(c_state);
      s_h[j] = (_Float16)hn;
      H_all_h[((size_t)b * T_ + t) * H_ + j] = (_Float16)hn;
    }
    __syncthreads();
  }
}

extern "C" void kernel_launch(void* const* d_in, const int* in_sizes, int n_in,
                              void* d_out, int out_size, void* d_ws, size_t ws_size,
                              hipStream_t stream) {
  const float* att_feats  = (const float*)d_in[0];
  const float* fc_feats   = (const float*)d_in[1];
  const int*   captions   = (const int*)  d_in[2];
  const float* count_vecs = (const float*)d_in[3];
  const float* embed_w    = (const float*)d_in[4];
  const float* cm_w1      = (const float*)d_in[5];
  const float* cm_b1      = (const float*)d_in[6];
  const float* cm_w2      = (const float*)d_in[7];
  const float* cm_b2      = (const float*)d_in[8];
  const float* att_hw     = (const float*)d_in[9];
  const float* att_hb     = (const float*)d_in[10];
  const float* att_fw     = (const float*)d_in[11];
  const float* att_fb     = (const float*)d_in[12];
  const float* alpha_w    = (const float*)d_in[13];
  const float* alpha_b    = (const float*)d_in[14];
  const float* fcproj_w   = (const float*)d_in[15];
  const float* fcproj_b   = (const float*)d_in[16];
  const float* w_ih       = (const float*)d_in[17];
  const float* b_ih       = (const float*)d_in[18];
  const float* w_hh       = (const float*)d_in[19];
  const float* b_hh       = (const float*)d_in[20];
  const float* fc_w       = (const float*)d_in[21];
  const float* fc_b       = (const float*)d_in[22];
  float* out = (float*)d_out;

  char* wsb = (char*)d_ws;
  size_t off = 0;
  auto nxt = [&](size_t bytes) { char* p = wsb + off; off += (bytes + 255) & ~(size_t)255; return p; };
  _Float16* att_th    = (_Float16*)nxt((size_t)B_*NN_*F_*2);
  _Float16* attW_h    = (_Float16*)nxt((size_t)B_*NN_*G4_*2);
  _Float16* attproj_h = (_Float16*)nxt((size_t)B_*NN_*A_*2);
  _Float16* we_h      = (_Float16*)nxt((size_t)B_*T_*E_*2);
  _Float16* H_all_h   = (_Float16*)nxt((size_t)B_*T_*H_*2);
  _Float16* w_ihF_h   = (_Float16*)nxt((size_t)G4_*F_*2);
  _Float16* w_ih0_h   = (_Float16*)nxt((size_t)G4_*E_*2);
  _Float16* wcnt_h    = (_Float16*)nxt((size_t)G4_*CD_*2);
  _Float16* fc_w_h    = (_Float16*)nxt((size_t)VP_*H_*2);
  _Float16* att_fw_h  = (_Float16*)nxt((size_t)A_*F_*2);
  _Float16* fcfeat_h  = (_Float16*)nxt((size_t)B_*F_*2);
  _Float16* whh_k     = (_Float16*)nxt((size_t)G4_*H_*2);
  _Float16* atthw_k   = (_Float16*)nxt((size_t)A_*H_*2);
  _Float16* fcproj_k  = (_Float16*)nxt((size_t)H_*F_*2);
  float*    we_proj   = (float*)nxt((size_t)B_*T_*G4_*4);
  float*    ce        = (float*)nxt((size_t)B_*CD_*4);
  if (off > ws_size) return;

  const size_t ALPHA_OFF = (size_t)B_ * T_ * V_;

  // ---- packs & small precompute ----
  transpose_att<<<dim3(F_/64, B_), 256, 0, stream>>>(att_feats, att_th);
  pack_h16<<<((size_t)B_*F_ + 255)/256, 256, 0, stream>>>(fc_feats, F_, 0, fcfeat_h, F_, B_, B_);
  pack_h16<<<((size_t)G4_*F_ + 255)/256, 256, 0, stream>>>(w_ih, E_+F_+CD_, E_, w_ihF_h, F_, G4_, G4_);
  pack_h16<<<((size_t)G4_*E_ + 255)/256, 256, 0, stream>>>(w_ih, E_+F_+CD_, 0, w_ih0_h, E_, G4_, G4_);
  pack_h16<<<((size_t)G4_*CD_ + 255)/256, 256, 0, stream>>>(w_ih, E_+F_+CD_, E_+F_, wcnt_h, CD_, G4_, G4_);
  pack_h16<<<((size_t)A_*F_ + 255)/256, 256, 0, stream>>>(att_fw, F_, 0, att_fw_h, F_, A_, A_);
  pack_h16<<<((size_t)VP_*H_ + 255)/256, 256, 0, stream>>>(fc_w, H_, 0, fc_w_h, H_, V_, VP_);
  pack_ki8<<<((size_t)G4_*H_ + 255)/256, 256, 0, stream>>>(w_hh, H_, 0, whh_k, G4_, H_);
  pack_ki8<<<((size_t)A_*H_ + 255)/256, 256, 0, stream>>>(att_hw, H_, 0, atthw_k, A_, H_);
  pack_ki8<<<((size_t)H_*F_ + 255)/256, 256, 0, stream>>>(fcproj_w, F_, 0, fcproj_k, H_, F_);
  count_embed_k<<<B_, 128, 0, stream>>>(count_vecs, cm_w1, cm_b1, cm_w2, cm_b2, ce);
  gather_we<<<B_ * T_, 128, 0, stream>>>(captions, embed_w, we_h);

  // ---- MFMA precompute GEMMs ----
  gemm_h16<1,1><<<dim3(A_/128, (B_*NN_)/128), 256, 0, stream>>>(
      att_th, F_, att_fw_h, F_, att_fb, attproj_h, A_, A_, F_);
  gemm_h16<1,0><<<dim3(G4_/128, (B_*NN_)/128), 256, 0, stream>>>(
      att_th, F_, w_ihF_h, F_, nullptr, attW_h, G4_, G4_, F_);
  gemm_h16<0,0><<<dim3(G4_/128, (B_*T_)/128), 256, 0, stream>>>(
      we_h, E_, w_ih0_h, E_, nullptr, we_proj, G4_, G4_, E_);

  // ---- persistent sequential loop ----
  seq_loop<<<B_, 1024, 0, stream>>>(fcfeat_h, fcproj_k, fcproj_b,
                                    wcnt_h, ce, b_ih, b_hh,
                                    atthw_k, att_hb,
                                    attproj_h, alpha_w, alpha_b,
                                    attW_h, we_proj, whh_k,
                                    H_all_h, out + ALPHA_OFF);

  // ---- logits = H_all @ fc_w^T + fc_b -> out (B*T, V) ----
  gemm_h16<0,1><<<dim3(VP_/128, (B_*T_)/128), 256, 0, stream>>>(
      H_all_h, H_, fc_w_h, H_, fc_b, out, V_, V_, H_);
}